// Round 5
// baseline (10170.122 us; speedup 1.0000x reference)
//
#include <hip/hip_runtime.h>
#include <hip/hip_bf16.h>
#include <stdint.h>
#include <math.h>

typedef __bf16 bf16;
typedef __bf16 bf16x8 __attribute__((ext_vector_type(8)));
typedef float f32x4 __attribute__((ext_vector_type(4)));

// B=8, H=W=128, dim=256, mid=128. fp32 I/O; internal hi/lo bf16 pairs.
// conv = 3-term bf16 (WhAh + WlAh + WhAl). A fragments read directly from
// global (L2-resident, fragment-direct layout -> coalesced dwordx4/lane);
// B staged as one hi-or-lo 3x130 slab in LDS, 40-elem pitch (2-way = free).

// ---------------- x: NCHW fp32 -> NHWC hi/lo bf16 (512 ch)
__global__ void k_x_split(const float* __restrict__ in, bf16* __restrict__ out) {
  __shared__ float t[32][33];
  const int b = blockIdx.z;
  const int p0 = blockIdx.x << 5, c0 = blockIdx.y << 5;
  const int tx = threadIdx.x, ty = threadIdx.y;  // block (32,8)
  const float* ib = in + (size_t)b * 256 * 16384;
  bf16* ob = out + (size_t)b * 16384 * 512;
#pragma unroll
  for (int k = 0; k < 32; k += 8)
    t[ty + k][tx] = ib[(size_t)(c0 + ty + k) * 16384 + p0 + tx];
  __syncthreads();
#pragma unroll
  for (int k = 0; k < 32; k += 8) {
    float v = t[tx][ty + k];
    bf16 hv = (bf16)v;
    bf16 lv = (bf16)(v - (float)hv);
    ob[(size_t)(p0 + ty + k) * 512 + c0 + tx] = hv;
    ob[(size_t)(p0 + ty + k) * 512 + 256 + c0 + tx] = lv;
  }
}

// ---------------- weight repack fp32 OIHW -> fragment-direct bf16
// layout: [tap][s][cb][coTotal][q*8+k]  (s=0 Wh, s=1 Wl; ci = cb*32+q*8+k)
__global__ void k_repackF(const float* __restrict__ src, bf16* __restrict__ dst,
                          int Cout, int Cin, int taps, int coutTotal, int coff) {
  int tid = blockIdx.x * 256 + threadIdx.x;
  int total = Cout * Cin * taps;
  if (tid >= total) return;
  int t = tid % taps;
  int rest = tid / taps;
  int ci = rest % Cin;
  int co = rest / Cin;
  float w = src[tid];
  bf16 wh = (bf16)w;
  bf16 wl = (bf16)(w - (float)wh);
  int nch = Cin >> 5;
  int cb = ci >> 5, q = (ci >> 3) & 3, k = ci & 7;
  size_t segAdv = (size_t)nch * coutTotal * 32;  // one s-segment
  size_t base = ((((size_t)t * 2) * nch + cb) * coutTotal + coff + co) * 32 + q * 8 + k;
  dst[base] = wh;
  dst[base + segAdv] = wl;
}

// ---------------- BN coefficients
__global__ void k_bncoef(const float* __restrict__ g, const float* __restrict__ b,
                         const float* __restrict__ m, const float* __restrict__ v,
                         float* __restrict__ sc, float* __restrict__ sh, int n) {
  int c = blockIdx.x * 256 + threadIdx.x;
  if (c >= n) return;
  float s = g[c] * (1.0f / sqrtf(v[c] + 1e-5f));
  sc[c] = s;
  sh[c] = b[c] - m[c] * s;
}

// ---------------- implicit-GEMM conv: A from global (L2), B slab in LDS
// in: hi/lo act tensor (hi at +0, lo at +Cin within rowStride-ch rows).
// Wr: fragment-direct (see k_repackF). out_mode: 0 = hi/lo bf16 NHWC
// (2*Cout ch), 1 = fp32 NHWC compact, 2 = fp32 NCHW. addbuf: hi/lo, 2*Cout.
__global__ __launch_bounds__(256, 4)
void k_conv(const bf16* __restrict__ in, int Cin, int rowStride,
            const bf16* __restrict__ Wr, int Cout, int ntaps,
            const float* __restrict__ scale, const float* __restrict__ shift,
            const bf16* __restrict__ addbuf, int relu,
            int out_mode, void* __restrict__ out) {
  __shared__ bf16 b_slab[3 * 130 * 40];  // one hi-or-lo plane, 40-elem pitch
  const int R = (ntaps == 9) ? 3 : 1;
  const int bx = blockIdx.x;
  const int bb = bx & 7, h = (bx >> 3) & 127;  // XCD swizzle: batch == XCD
  const int row = bb * 128 + h;
  const int co_block = blockIdx.y << 7;
  const int tid = threadIdx.x;
  const int lane = tid & 63, wave = tid >> 6;
  const int wm = (wave >> 1) << 6, wn = (wave & 1) << 6;
  const int quad = lane >> 4, l15 = lane & 15;
  const int nchunks = Cin >> 5;
  const size_t segAdv = (size_t)nchunks * Cout * 32;  // Wh->Wl advance

  f32x4 acc[4][4];
#pragma unroll
  for (int i = 0; i < 4; ++i)
#pragma unroll
    for (int j = 0; j < 4; ++j)
#pragma unroll
      for (int r = 0; r < 4; ++r) acc[i][j][r] = 0.0f;

  for (int cb = 0; cb < nchunks; ++cb) {
    for (int hl = 0; hl < 2; ++hl) {
      __syncthreads();  // protect slab from prior readers
      const int total_units = R * 130 * 4;  // 16B pieces
      for (int u = tid; u < total_units; u += 256) {
        int piece = u & 3, rp = u >> 2;
        int r = rp / 130, p = rp - r * 130;
        int hi2 = h + r - (R == 3 ? 1 : 0);
        int wi = p - 1;
        uint4 v;
        v.x = v.y = v.z = v.w = 0u;
        if ((unsigned)hi2 < 128u && (unsigned)wi < 128u)
          v = *(const uint4*)(in + (size_t)((bb * 128 + hi2) * 128 + wi) * rowStride
                              + hl * Cin + cb * 32 + piece * 8);
        *(uint4*)&b_slab[(r * 130 + p) * 40 + piece * 8] = v;
      }
      __syncthreads();
      for (int tap = 0; tap < ntaps; ++tap) {
        const int rr = (R == 3) ? (tap / 3) : 0;
        const int wc = (R == 3) ? (tap % 3) : 1;
        const bf16* baseH = Wr + (((size_t)(tap * 2) * nchunks + cb) * Cout + co_block) * 32;
        bf16x8 bfr[4];
#pragma unroll
        for (int j = 0; j < 4; ++j)
          bfr[j] = *(const bf16x8*)&b_slab[(rr * 130 + wn + j * 16 + l15 + wc) * 40 + quad * 8];
        if (hl == 0) {
          bf16x8 afH[4], afL[4];
#pragma unroll
          for (int i = 0; i < 4; ++i) {
            const size_t ao = (size_t)(wm + i * 16 + l15) * 32 + quad * 8;
            afH[i] = *(const bf16x8*)(baseH + ao);
            afL[i] = *(const bf16x8*)(baseH + segAdv + ao);
          }
#pragma unroll
          for (int i = 0; i < 4; ++i)
#pragma unroll
            for (int j = 0; j < 4; ++j) {
              acc[i][j] = __builtin_amdgcn_mfma_f32_16x16x32_bf16(afH[i], bfr[j], acc[i][j], 0, 0, 0);
              acc[i][j] = __builtin_amdgcn_mfma_f32_16x16x32_bf16(afL[i], bfr[j], acc[i][j], 0, 0, 0);
            }
        } else {
          bf16x8 afH[4];
#pragma unroll
          for (int i = 0; i < 4; ++i)
            afH[i] = *(const bf16x8*)(baseH + (size_t)(wm + i * 16 + l15) * 32 + quad * 8);
#pragma unroll
          for (int i = 0; i < 4; ++i)
#pragma unroll
            for (int j = 0; j < 4; ++j)
              acc[i][j] = __builtin_amdgcn_mfma_f32_16x16x32_bf16(afH[i], bfr[j], acc[i][j], 0, 0, 0);
        }
      }
    }
  }

  // epilogue: D row(m=cout)=quad*4+reg, col(n=pos)=lane&15
#pragma unroll
  for (int i = 0; i < 4; ++i) {
    const int co = co_block + wm + i * 16 + (quad << 2);
#pragma unroll
    for (int j = 0; j < 4; ++j) {
      const int pos = wn + j * 16 + l15;
      float v[4];
#pragma unroll
      for (int r = 0; r < 4; ++r) v[r] = acc[i][j][r];
      if (scale) {
#pragma unroll
        for (int r = 0; r < 4; ++r) v[r] = v[r] * scale[co + r] + shift[co + r];
      }
      if (addbuf) {
        const bf16* ah = addbuf + (size_t)(row * 128 + pos) * (2 * Cout) + co;
        const bf16* al = ah + Cout;
#pragma unroll
        for (int r = 0; r < 4; ++r) v[r] += (float)ah[r] + (float)al[r];
      }
      if (relu) {
#pragma unroll
        for (int r = 0; r < 4; ++r) v[r] = fmaxf(v[r], 0.0f);
      }
      if (out_mode == 0) {
        bf16* ob = (bf16*)out;
        union { bf16 hv[4]; uint2 u; } ph, pl;
#pragma unroll
        for (int r = 0; r < 4; ++r) {
          ph.hv[r] = (bf16)v[r];
          pl.hv[r] = (bf16)(v[r] - (float)ph.hv[r]);
        }
        const size_t base = (size_t)(row * 128 + pos) * (2 * Cout);
        *(uint2*)&ob[base + co] = ph.u;
        *(uint2*)&ob[base + Cout + co] = pl.u;
      } else if (out_mode == 1) {
        float* of = (float*)out;
        float4 pk = make_float4(v[0], v[1], v[2], v[3]);
        *(float4*)&of[(size_t)(row * 128 + pos) * Cout + co] = pk;
      } else {
        float* of = (float*)out;
#pragma unroll
        for (int r = 0; r < 4; ++r)
          of[((size_t)(bb * Cout + co + r) * 128 + h) * 128 + pos] = v[r];
      }
    }
  }
}

// ---------------- pools (fp32 reconstruct, scan, re-split), in-place
// y: 512ch rows [lookH 0:128 | pH 128:256 | lookL 256:384 | pL 384:512]
__global__ void k_pool_s1(bf16* __restrict__ y) {  // left_pool: scan w
  int tid = blockIdx.x * 256 + threadIdx.x;
  int c = tid & 127, h = (tid >> 7) & 127, b = tid >> 14;
  bf16* base = y + (size_t)((b * 128 + h) * 128) * 512;
  float run = -INFINITY;
  for (int w = 127; w >= 0; --w) {
    bf16* p = base + (size_t)w * 512;
    float look = (float)p[c] + (float)p[256 + c];
    float padd = (float)p[128 + c] + (float)p[384 + c];
    run = fmaxf(run, look);
    float sum = run + padd;
    bf16 hv = (bf16)sum;
    p[c] = hv;
    p[128 + c] = (bf16)(sum - (float)hv);
  }
}
__global__ void k_pool_s2(bf16* __restrict__ y) {  // top_pool: scan h
  int tid = blockIdx.x * 256 + threadIdx.x;
  int c = tid & 127, w = (tid >> 7) & 127, b = tid >> 14;
  bf16* base = y + ((size_t)b * 16384 + w) * 512;
  float run = -INFINITY;
  for (int hh = 127; hh >= 0; --hh) {
    bf16* p = base + (size_t)hh * 65536;
    float look = (float)p[c] + (float)p[256 + c];
    float padd = (float)p[128 + c] + (float)p[384 + c];
    run = fmaxf(run, look);
    float sum = run + padd;
    bf16 hv = (bf16)sum;
    p[c] = hv;
    p[128 + c] = (bf16)(sum - (float)hv);
  }
}
__global__ void k_tpool_f(float* __restrict__ buf) {  // in-place top_pool fp32
  int tid = blockIdx.x * 256 + threadIdx.x;
  int c = tid & 127, w = (tid >> 7) & 127, b = tid >> 14;
  float* p = buf + ((size_t)b * 16384 + w) * 128 + c;
  float run = -INFINITY;
  for (int hh = 127; hh >= 0; --hh) {
    run = fmaxf(run, p[(size_t)hh * 16384]);
    p[(size_t)hh * 16384] = run;
  }
}
__global__ void k_lpool_add_f(const float* __restrict__ in, const float* __restrict__ addb,
                              bf16* __restrict__ out) {
  int tid = blockIdx.x * 256 + threadIdx.x;
  int c = tid & 127, h = (tid >> 7) & 127, b = tid >> 14;
  const float* p = in + (size_t)((b * 128 + h) * 128) * 128 + c;
  const float* a = addb + (size_t)((b * 128 + h) * 128) * 128 + c;
  bf16* o = out + (size_t)((b * 128 + h) * 128) * 256;
  float run = -INFINITY;
  for (int w = 127; w >= 0; --w) {
    run = fmaxf(run, p[(size_t)w * 128]);
    float sum = run + a[(size_t)w * 128];
    bf16 hv = (bf16)sum;
    o[(size_t)w * 256 + c] = hv;
    o[(size_t)w * 256 + 128 + c] = (bf16)(sum - (float)hv);
  }
}

extern "C" void kernel_launch(void* const* d_in, const int* in_sizes, int n_in,
                              void* d_out, int out_size, void* d_ws, size_t ws_size,
                              hipStream_t stream) {
  (void)in_sizes; (void)n_in; (void)out_size; (void)ws_size;
#define INF(i) ((const float*)d_in[i])
  char* ws = (char*)d_ws;
  const size_t MB = 1 << 20;
  // weights [0, ~9.75MB): fragment-direct
  bf16* wrA  = (bf16*)(ws + 0);          // 9 taps x2 x 256co x 256ci
  bf16* wrB  = (bf16*)(ws + 2359296);
  bf16* wrp1 = (bf16*)(ws + 4718592);    // 9x2x128x128
  bf16* wrp2 = (bf16*)(ws + 5308416);
  bf16* wrpc = (bf16*)(ws + 5898240);    // 9x2x256x128
  bf16* wrc1 = (bf16*)(ws + 7077888);    // 1x2x256x256
  bf16* wrc2 = (bf16*)(ws + 7340032);    // 9x2x256x256
  float* scA  = (float*)(ws + 9699328);
  float* shA  = (float*)(ws + 9703424);
  float* scB  = (float*)(ws + 9707520);
  float* shB  = (float*)(ws + 9711616);
  float* scp  = (float*)(ws + 9715712);
  float* shp  = (float*)(ws + 9719808);
  float* scb  = (float*)(ws + 9723904);
  float* shb  = (float*)(ws + 9728000);
  float* scc2 = (float*)(ws + 9732096);
  float* shc2 = (float*)(ws + 9736192);
  // activations (ws use <= 330 MB; d_out doubles as 128 MB scratch)
  bf16*  x_hl  = (bf16*)(ws + 10 * MB);    // 128 MB, live thru step 8
  bf16*  bnrel = (bf16*)(ws + 138 * MB);   // 128 MB: bn1 -> relu1 in-place
  float* p1lk  = (float*)(ws + 266 * MB);  // 64 MB fp32
  float* p2lk  = (float*)(ws + 10 * MB);   // 64 MB fp32 over dead x_hl
  bf16*  psum  = (bf16*)(ws + 74 * MB);    // 64 MB hi/lo compact 256ch
  bf16*  yscr  = (bf16*)d_out;             // 128 MB scratch: yA/s1 then yB/s2

  // 1) x -> NHWC hi/lo
  k_x_split<<<dim3(512, 8, 8), dim3(32, 8), 0, stream>>>(INF(0), x_hl);

  // 2) weight repacks (fragment-direct, Wh/Wl segments)
  k_repackF<<<1152, 256, 0, stream>>>(INF(1),  wrA,  128, 256, 9, 256, 0);
  k_repackF<<<1152, 256, 0, stream>>>(INF(6),  wrA,  128, 256, 9, 256, 128);
  k_repackF<<<1152, 256, 0, stream>>>(INF(11), wrB,  128, 256, 9, 256, 0);
  k_repackF<<<1152, 256, 0, stream>>>(INF(16), wrB,  128, 256, 9, 256, 128);
  k_repackF<<<576,  256, 0, stream>>>(INF(21), wrp1, 128, 128, 9, 128, 0);
  k_repackF<<<576,  256, 0, stream>>>(INF(22), wrp2, 128, 128, 9, 128, 0);
  k_repackF<<<1152, 256, 0, stream>>>(INF(23), wrpc, 256, 128, 9, 256, 0);
  k_repackF<<<256,  256, 0, stream>>>(INF(28), wrc1, 256, 256, 1, 256, 0);
  k_repackF<<<2304, 256, 0, stream>>>(INF(33), wrc2, 256, 256, 9, 256, 0);

  // 3) BN coefficients
  k_bncoef<<<1, 256, 0, stream>>>(INF(2),  INF(3),  INF(4),  INF(5),  scA,       shA,       128);
  k_bncoef<<<1, 256, 0, stream>>>(INF(7),  INF(8),  INF(9),  INF(10), scA + 128, shA + 128, 128);
  k_bncoef<<<1, 256, 0, stream>>>(INF(12), INF(13), INF(14), INF(15), scB,       shB,       128);
  k_bncoef<<<1, 256, 0, stream>>>(INF(17), INF(18), INF(19), INF(20), scB + 128, shB + 128, 128);
  k_bncoef<<<1, 256, 0, stream>>>(INF(24), INF(25), INF(26), INF(27), scp, shp, 256);
  k_bncoef<<<1, 256, 0, stream>>>(INF(29), INF(30), INF(31), INF(32), scb, shb, 256);
  k_bncoef<<<1, 256, 0, stream>>>(INF(34), INF(35), INF(36), INF(37), scc2, shc2, 256);

  // 4) bn1 = BN(conv1x1(x)) -> bnrel (hi/lo)
  k_conv<<<dim3(1024, 2), 256, 0, stream>>>(x_hl, 256, 512, wrc1, 256, 1, scb, shb, nullptr, 0, 0, bnrel);
  // 5) yA = [look_conv1 | p1_conv1] (BN+ReLU) -> d_out scratch
  k_conv<<<dim3(1024, 2), 256, 0, stream>>>(x_hl, 256, 512, wrA, 256, 9, scA, shA, nullptr, 1, 0, yscr);
  // 6) s1 = left_pool(look1) + p1_conv1 (in-place, ch [0:256))
  k_pool_s1<<<512, 256, 0, stream>>>(yscr);
  // 7) p1_look = conv(s1, p1lc) -> fp32
  k_conv<<<dim3(1024, 1), 256, 0, stream>>>(yscr, 128, 512, wrp1, 128, 9, nullptr, nullptr, nullptr, 0, 1, p1lk);
  // 8) yB = [look_conv2 | p2_conv1] -> d_out scratch (x dead after)
  k_conv<<<dim3(1024, 2), 256, 0, stream>>>(x_hl, 256, 512, wrB, 256, 9, scB, shB, nullptr, 1, 0, yscr);
  // 9) s2 = top_pool(look2) + p2_conv1 (in-place)
  k_pool_s2<<<512, 256, 0, stream>>>(yscr);
  // 10) p2_look = conv(s2, p2lc) -> fp32 (over dead x_hl)
  k_conv<<<dim3(1024, 1), 256, 0, stream>>>(yscr, 128, 512, wrp2, 128, 9, nullptr, nullptr, nullptr, 0, 1, p2lk);
  // 11) ptmp = top_pool(p1_look) in-place
  k_tpool_f<<<512, 256, 0, stream>>>(p1lk);
  // 12) psum = left_pool(p2_look) + ptmp -> hi/lo compact
  k_lpool_add_f<<<512, 256, 0, stream>>>(p2lk, p1lk, psum);
  // 13) relu1 = relu(BN(conv(psum, pconv1)) + bn1) in-place over bn1
  k_conv<<<dim3(1024, 2), 256, 0, stream>>>(psum, 128, 256, wrpc, 256, 9, scp, shp, bnrel, 1, 0, bnrel);
  // 14) out = relu(BN(conv(relu1, c2))) -> NCHW fp32 d_out
  k_conv<<<dim3(1024, 2), 256, 0, stream>>>(bnrel, 256, 512, wrc2, 256, 9, scc2, shc2, nullptr, 1, 2, (float*)d_out);
#undef INF
}